// Round 6
// baseline (70.805 us; speedup 1.0000x reference)
//
#include <hip/hip_runtime.h>

// Polyphase resample up=3 down=2, N=2097152, L=129 taps, start=(L-1)/2=64.
// out[3j+0] = 3 * sum_i x[21+2j-i] * h[1+3i]   (i in [0,43))
// out[3j+1] = 3 * sum_i x[22+2j-i] * h[0+3i]
// out[3j+2] = 3 * sum_i x[22+2j-i] * h[2+3i]
// (formula verified across R0-R7, absmax 0.25)
//
// R8: R7 is clean (no spill, kernel ~11us) but latency-bound at 4 waves/
// SIMD (grid 1024 blocks caps occupancy; VGPR=64 already permits 8).
// Halve per-thread work G=4->2 => 2048 blocks => 8 waves/SIMD, doubling
// latency hiding. do_chunk formula is G-generic; structure keeps the
// COMPILER LAW (chunks behind #pragma unroll 1, else ds_reads hoist+spill;
// proven R3/R6 vs R0/R7).
// Padding change: per-thread base is now 4*tid, so pad-per-8 loses
// compile-time pad offsets. Use pad 1-per-4: p = q + (q>>2); lane stride
// 5 words = 2 lanes/bank = free; staging float4 -> xs[5*q4 + 0..3];
// window addr = 5*tid + 5*(D>>2) + R' + k + ((R'+k)>>2), R' = D&3.

#define N_SIG   2097152
#define L_FILT  129
#define NTAPS   43
#define G       2            // output groups per thread (6 outputs)
#define BLK     256
#define GROUPS_PER_BLK (BLK * G)             // 512 groups -> 1536 outputs/block
#define TILE_Q  1072                         // covers q in [3, 2*GPB+44=1068]
#define TILE_P  (TILE_Q + TILE_Q / 4)        // 1340 words, pad 1 per 4

// One tap-chunk of U taps starting at runtime i0. D = 45-(i0+U-1);
// RP = D&3 must be compile-time so per-k pad offsets ((RP+k)>>2) are
// immediates. Window length U + 2*G - 1.
template <int U, int RP>
__device__ __forceinline__ void do_chunk(const float* __restrict__ xs,
                                         const float* __restrict__ h,
                                         int i0, int tid, float (&acc)[3 * G]) {
    const int D = 45 - (i0 + U - 1);            // window base in d-space (runtime)
    const int pb = 5 * tid + 5 * (D >> 2) + RP; // padded word addr of window[0]
    float wz[U + 2 * G - 1];                    // window words
#pragma unroll
    for (int k = 0; k < U + 2 * G - 1; ++k)
        wz[k] = xs[pb + k + ((RP + k) >> 2)];   // const offsets, stride-5 lanes
#pragma unroll
    for (int u = 0; u < U; ++u) {
        // wave-uniform indices -> scalar loads, SGPR operands in the FMAs
        const float h0 = h[3 * (i0 + u) + 0];
        const float h1 = h[3 * (i0 + u) + 1];
        const float h2 = h[3 * (i0 + u) + 2];
#pragma unroll
        for (int g = 0; g < G; ++g) {
            const float xa = wz[(U - 1 - u) + 2 * g];      // x[21+2j-i]
            const float xb = wz[(U - 1 - u) + 2 * g + 1];  // x[22+2j-i]
            acc[3 * g + 0] += xa * h1;
            acc[3 * g + 1] += xb * h0;
            acc[3 * g + 2] += xb * h2;
        }
    }
}

__global__ __launch_bounds__(BLK, 8) void poly_kernel(
    const float* __restrict__ x, const float* __restrict__ h,
    float* __restrict__ out, int n_out)
{
    __shared__ float xs[TILE_P];

    const int tid = threadIdx.x;
    const int b   = blockIdx.x;

    // Tile base: local group jl uses x[2*GPB*b + {21,22} + 2*jl - i];
    // tb puts needed words at q = {45,46} + 2*jl - i in [3, 2*GPB+44].
    const int tb = 2 * GROUPS_PER_BLK * b - 24;

    // Coalesced staging with zero-pad at edges. Logical word q = 4*q4 + j
    // lives at p = 5*q4 + j (pad 1 per 4; float4 never straddles a pad).
    for (int q4 = tid; q4 < TILE_Q / 4; q4 += BLK) {
        const int gx = tb + 4 * q4;
        float4 v;
        if (gx >= 0 && gx + 3 < N_SIG) {
            v = *(const float4*)(x + gx);
        } else {
            v.x = (gx     >= 0 && gx     < N_SIG) ? x[gx]     : 0.0f;
            v.y = (gx + 1 >= 0 && gx + 1 < N_SIG) ? x[gx + 1] : 0.0f;
            v.z = (gx + 2 >= 0 && gx + 2 < N_SIG) ? x[gx + 2] : 0.0f;
            v.w = (gx + 3 >= 0 && gx + 3 < N_SIG) ? x[gx + 3] : 0.0f;
        }
        const int p = 5 * q4;
        xs[p + 0] = v.x; xs[p + 1] = v.y; xs[p + 2] = v.z; xs[p + 3] = v.w;
    }
    __syncthreads();

    float acc[3 * G];
#pragma unroll
    for (int k = 0; k < 3 * G; ++k) acc[k] = 0.0f;

    // 2 chunks of 16 taps (D = 30-i0+..: D&3 == 2 for both) + tail of 11
    // (D = 3, D&3 == 3). Rolled loop: opaque backedge blocks hoisting.
#pragma unroll 1
    for (int i0 = 0; i0 < 32; i0 += 16)
        do_chunk<16, 2>(xs, h, i0, tid, acc);
    do_chunk<11, 3>(xs, h, 32, tid, acc);

    // 6 contiguous outputs per thread; 3x float2 (8B-aligned, coalesced).
    // Fold the up=3 gain here.
    const int ob = 3 * GROUPS_PER_BLK * b + 3 * G * tid;
#pragma unroll
    for (int k = 0; k < 3; ++k) {
        if (ob + 2 * k + 1 < n_out) {
            *(float2*)(out + ob + 2 * k) =
                make_float2(3.0f * acc[2 * k + 0], 3.0f * acc[2 * k + 1]);
        }
    }
}

extern "C" void kernel_launch(void* const* d_in, const int* in_sizes, int n_in,
                              void* d_out, int out_size, void* d_ws, size_t ws_size,
                              hipStream_t stream) {
    const float* x = (const float*)d_in[0];
    const float* h = (const float*)d_in[1];
    float* out = (float*)d_out;
    const int blocks = (out_size + 3 * GROUPS_PER_BLK - 1) / (3 * GROUPS_PER_BLK);
    poly_kernel<<<blocks, BLK, 0, stream>>>(x, h, out, out_size);
}